// Round 1
// baseline (104.802 us; speedup 1.0000x reference)
//
#include <hip/hip_runtime.h>
#include <math.h>

#define GH 47
#define GW 47
#define NWIN (GH*GW)   // 2209
#define NB 32
#define KSEL 16

// ---------------------------------------------------------------------------
// Kernel 1: per-window variance. One 64-lane wave per 16x16x3 window.
// Window sums accumulated in double so our top-k ranking matches the f32 ref.
// ---------------------------------------------------------------------------
__global__ __launch_bounds__(256) void k_var(const float* __restrict__ x,
                                             float* __restrict__ var)
{
    int wid  = blockIdx.x * 4 + (threadIdx.x >> 6);   // window id, 0..70687
    int lane = threadIdx.x & 63;
    int b   = wid / NWIN;
    int rem = wid - b * NWIN;
    int gy  = rem / GW;
    int gx  = rem - gy * GW;
    int h0 = gy * 8, w0 = gx * 8;

    double s = 0.0, s2 = 0.0;
    #pragma unroll
    for (int c = 0; c < 3; ++c) {
        // 64 lanes cover one channel's 16x16 window as 16 rows x 4 float4
        int y  = lane >> 2;
        int x4 = lane & 3;
        const float4 v = *reinterpret_cast<const float4*>(
            x + (((size_t)(b*3 + c) * 384 + (h0 + y)) * 384 + w0 + x4*4));
        s  += (double)v.x + (double)v.y + (double)v.z + (double)v.w;
        s2 += (double)v.x*v.x + (double)v.y*v.y + (double)v.z*v.z + (double)v.w*v.w;
    }
    #pragma unroll
    for (int m = 1; m < 64; m <<= 1) {
        s  += __shfl_xor(s,  m, 64);
        s2 += __shfl_xor(s2, m, 64);
    }
    if (lane == 0) {
        const double n = 768.0;
        var[wid] = (float)((s2 - s*s/n) / (n - 1.0));
    }
}

// ---------------------------------------------------------------------------
// Kernel 2: per-batch top-16 (iterative argmax, tie -> smaller index),
// then the reference's (buggy) idx->coord decode with dynamic_slice clamping.
// ---------------------------------------------------------------------------
__global__ __launch_bounds__(256) void k_topk(const float* __restrict__ var,
                                              int* __restrict__ coords)
{
    __shared__ float lv[NWIN];
    __shared__ float s_val[4];
    __shared__ int   s_idx[4];
    __shared__ int   chosen[KSEL];
    int b = blockIdx.x, tid = threadIdx.x;
    int lane = tid & 63, wavid = tid >> 6;

    for (int i = tid; i < NWIN; i += 256) lv[i] = var[b*NWIN + i];
    __syncthreads();

    for (int k = 0; k < KSEL; ++k) {
        float bv = -INFINITY; int bi = NWIN;
        for (int i = tid; i < NWIN; i += 256) {
            float v = lv[i];
            if (v > bv) { bv = v; bi = i; }
        }
        #pragma unroll
        for (int m = 1; m < 64; m <<= 1) {
            float ov = __shfl_xor(bv, m, 64);
            int   oi = __shfl_xor(bi, m, 64);
            if (ov > bv || (ov == bv && oi < bi)) { bv = ov; bi = oi; }
        }
        if (lane == 0) { s_val[wavid] = bv; s_idx[wavid] = bi; }
        __syncthreads();
        if (tid == 0) {
            float cv = s_val[0]; int ci = s_idx[0];
            #pragma unroll
            for (int wv = 1; wv < 4; ++wv) {
                if (s_val[wv] > cv || (s_val[wv] == cv && s_idx[wv] < ci)) {
                    cv = s_val[wv]; ci = s_idx[wv];
                }
            }
            chosen[k] = ci;
            lv[ci] = -INFINITY;
        }
        __syncthreads();
    }

    if (tid < KSEL) {
        int idx = chosen[tid];
        int h = (idx / 48) * 8; if (h > 320) h = 320;   // buggy divisor 48, then clamp
        int w = (idx % 48) * 8; if (w > 320) w = 320;
        coords[(b*KSEL + tid)*2 + 0] = h;
        coords[(b*KSEL + tid)*2 + 1] = w;
    }
}

// ---------------------------------------------------------------------------
// Kernel 3: fused encoder per patch. One block (256 thr) per patch.
// conv1 computed per-thread-row into registers; conv2+spatial-mean collapsed
// into S[ic][ky][kx] decimated sums + a 64x288 matvec.
// ---------------------------------------------------------------------------
#define STR 67   // LDS row stride (floats); 2*STR mod 32banks spreads lanes
__global__ __launch_bounds__(256, 2) void k_encode(const float* __restrict__ x,
    const float* __restrict__ w1, const float* __restrict__ b1,
    const float* __restrict__ w2, const float* __restrict__ b2,
    const int* __restrict__ coords, float* __restrict__ pfeats)
{
    __shared__ float s_in[3][65][STR];  // [c][1+y][1+x], row 0 / col 0 = zero pad
    __shared__ float s_w1[864];
    __shared__ float s_S[32][9];

    int p = blockIdx.x;
    int b = p >> 4;
    int tid = threadIdx.x;
    int h0 = coords[p*2 + 0];
    int w0 = coords[p*2 + 1];

    float* si = &s_in[0][0][0];
    for (int i = tid; i < 3*65*STR; i += 256) si[i] = 0.f;
    for (int i = tid; i < 864; i += 256) s_w1[i] = w1[i];
    __syncthreads();

    // stage 3x64x64 patch into LDS (float4 global loads, scalar LDS stores)
    #pragma unroll
    for (int it = 0; it < 12; ++it) {
        int fi = tid + it*256;            // 0..3071
        int c   = fi >> 10;
        int rem = fi & 1023;
        int y   = rem >> 4;
        int x4  = rem & 15;
        const float4 v = *reinterpret_cast<const float4*>(
            x + (((size_t)(b*3 + c) * 384 + (h0 + y)) * 384 + w0 + x4*4));
        float* dst = &s_in[c][1+y][1 + x4*4];
        dst[0] = v.x; dst[1] = v.y; dst[2] = v.z; dst[3] = v.w;
    }
    __syncthreads();

    int icl = tid >> 5;        // 0..7
    int iy  = tid & 31;        // conv1 output row 0..31
    bool odd = (iy & 1) != 0;

    #pragma unroll
    for (int chunk = 0; chunk < 4; ++chunk) {
        int ic = chunk*8 + icl;
        float acc[32];
        #pragma unroll
        for (int i = 0; i < 32; ++i) acc[i] = 0.f;

        #pragma unroll
        for (int ch = 0; ch < 3; ++ch) {
            #pragma unroll
            for (int ky = 0; ky < 3; ++ky) {
                const float* row = &s_in[ch][2*iy + ky][0];
                float wA = s_w1[ic*27 + ch*9 + ky*3 + 0];
                float wB = s_w1[ic*27 + ch*9 + ky*3 + 1];
                float wC = s_w1[ic*27 + ch*9 + ky*3 + 2];
                float rb[65];
                #pragma unroll
                for (int j = 0; j < 65; ++j) rb[j] = row[j];
                #pragma unroll
                for (int ix = 0; ix < 32; ++ix)
                    acc[ix] = fmaf(rb[2*ix], wA,
                               fmaf(rb[2*ix+1], wB,
                                fmaf(rb[2*ix+2], wC, acc[ix])));
            }
        }

        float bias = b1[ic];
        // column sums of relu(conv1 row):
        // c0: odd ix <= 29 (kx=0) ; c1: even ix (kx=1) ; c2: odd ix (kx=2)
        float c0 = 0.f, c1 = 0.f, c2 = 0.f;
        #pragma unroll
        for (int ix = 0; ix < 32; ++ix) {
            float v = acc[ix] + bias;
            v = v > 0.f ? v : 0.f;
            if (ix & 1) { if (ix < 31) c0 += v; c2 += v; }
            else        { c1 += v; }
        }
        // row validity per conv2 ky:  ky=0: odd iy<=29 ; ky=1: even iy ; ky=2: odd iy
        bool k0v = odd && (iy < 31);
        bool k1v = !odd;
        bool k2v = odd;
        float pv[9];
        pv[0] = k0v ? c0 : 0.f; pv[1] = k0v ? c1 : 0.f; pv[2] = k0v ? c2 : 0.f;
        pv[3] = k1v ? c0 : 0.f; pv[4] = k1v ? c1 : 0.f; pv[5] = k1v ? c2 : 0.f;
        pv[6] = k2v ? c0 : 0.f; pv[7] = k2v ? c1 : 0.f; pv[8] = k2v ? c2 : 0.f;
        #pragma unroll
        for (int m = 1; m <= 16; m <<= 1) {
            #pragma unroll
            for (int k = 0; k < 9; ++k) pv[k] += __shfl_xor(pv[k], m, 64);
        }
        if (iy == 0) {
            #pragma unroll
            for (int k = 0; k < 9; ++k) s_S[ic][k] = pv[k];
        }
    }
    __syncthreads();

    // feats[oc] = b2[oc] + (1/256) * sum_j w2[oc][j] * S[j]
    if (tid < 64) {
        const float* Sf = &s_S[0][0];
        float a = 0.f;
        for (int j = 0; j < 288; ++j)
            a = fmaf(w2[tid*288 + j], Sf[j], a);
        pfeats[p*64 + tid] = b2[tid] + a * (1.0f/256.0f);
    }
}

// ---------------------------------------------------------------------------
// Kernel 4: mean over the 16 patches -> out[32][64]
// ---------------------------------------------------------------------------
__global__ __launch_bounds__(256) void k_reduce(const float* __restrict__ pfeats,
                                                float* __restrict__ out)
{
    int g = blockIdx.x*256 + threadIdx.x;
    if (g >= NB*64) return;
    int b = g >> 6, oc = g & 63;
    float s = 0.f;
    #pragma unroll
    for (int k = 0; k < KSEL; ++k) s += pfeats[(b*KSEL + k)*64 + oc];
    out[g] = s * (1.0f/16.0f);
}

extern "C" void kernel_launch(void* const* d_in, const int* in_sizes, int n_in,
                              void* d_out, int out_size, void* d_ws, size_t ws_size,
                              hipStream_t stream)
{
    const float* x  = (const float*)d_in[0];
    const float* w1 = (const float*)d_in[1];
    const float* b1 = (const float*)d_in[2];
    const float* w2 = (const float*)d_in[3];
    const float* b2 = (const float*)d_in[4];
    float* out = (float*)d_out;

    char* ws = (char*)d_ws;
    float* var    = (float*)ws;                               // 70688 f
    int*   coords = (int*)(ws + (size_t)NB*NWIN*4);           // 1024 i
    float* pfeats = (float*)(ws + (size_t)NB*NWIN*4 + 4096);  // 512*64 f

    k_var   <<<(NB*NWIN)/4, 256, 0, stream>>>(x, var);
    k_topk  <<<NB,          256, 0, stream>>>(var, coords);
    k_encode<<<NB*KSEL,     256, 0, stream>>>(x, w1, b1, w2, b2, coords, pfeats);
    k_reduce<<<8,           256, 0, stream>>>(pfeats, out);
}

// Round 2
// 73.806 us; speedup vs baseline: 1.4200x; 1.4200x over previous
//
#include <hip/hip_runtime.h>
#include <math.h>

#define NB 32
#define GH 47
#define GW 47
#define NWIN (GH*GW)   // 2209
#define KSEL 16
#define RPITCH 17      // float4 per LDS row in k_encode (68 floats)

// ---------------------------------------------------------------------------
// Kernel 1: per-window variance via separable f64 window sums.
// block = (gyp, b): computes windows gy in {2gyp, 2gyp+1}, all 47 gx.
// ---------------------------------------------------------------------------
__global__ __launch_bounds__(256) void k_var(const float* __restrict__ x,
                                             float* __restrict__ var)
{
    __shared__ double hs [3][24][GW];
    __shared__ double hs2[3][24][GW];
    int gyp = blockIdx.x;     // 0..23
    int b   = blockIdx.y;
    int tid = threadIdx.x;
    int R0  = gyp * 16;

    // horizontal 16-wide sums: task = (c, rr, gx)
    for (int tau = tid; tau < 3*24*GW; tau += 256) {
        int gx = tau % GW;
        int t2 = tau / GW;
        int rr = t2 % 24;
        int c  = t2 / 24;
        int row = R0 + rr;
        double s = 0.0, s2 = 0.0;
        if (row < 384) {
            const float* px = x + (((size_t)(b*3 + c)*384 + row)*384 + gx*8);
            #pragma unroll
            for (int q = 0; q < 4; ++q) {
                float4 v = *reinterpret_cast<const float4*>(px + q*4);
                double a0 = v.x, a1 = v.y, a2 = v.z, a3 = v.w;
                s  += a0 + a1 + a2 + a3;
                s2 = fma(a0,a0, fma(a1,a1, fma(a2,a2, fma(a3,a3, s2))));
            }
        }
        hs [c][rr][gx] = s;
        hs2[c][rr][gx] = s2;
    }
    __syncthreads();

    int w = tid;
    if (w < 2*GW) {
        int g = w / GW, gx = w % GW;
        int gy = gyp*2 + g;
        if (gy < GH) {
            double S = 0.0, S2 = 0.0;
            #pragma unroll
            for (int c = 0; c < 3; ++c)
                #pragma unroll
                for (int r = 0; r < 16; ++r) {
                    S  += hs [c][g*8 + r][gx];
                    S2 += hs2[c][g*8 + r][gx];
                }
            var[(size_t)b*NWIN + gy*GW + gx] =
                (float)((S2 - S*S/768.0) / 767.0);
        }
    }
}

// ---------------------------------------------------------------------------
// Kernel 2: per-batch top-16, single wave, register-resident u64 keys.
// key = (monotonic-f32-bits << 12) | (4095 - idx): max => largest v, tie ->
// smaller idx (matches jax.lax.top_k stable order). Buggy /48 decode + clamp.
// ---------------------------------------------------------------------------
__global__ void k_topk(const float* __restrict__ var, int* __restrict__ coords)
{
    int b = blockIdx.x, l = threadIdx.x;   // 64 threads
    unsigned long long key[35];
    #pragma unroll
    for (int j = 0; j < 35; ++j) {
        int idx = j*64 + l;
        unsigned long long kk = 0ULL;
        if (idx < NWIN) {
            unsigned u = __float_as_uint(var[(size_t)b*NWIN + idx]);
            unsigned mono = u ^ ((unsigned)((int)u >> 31) | 0x80000000u);
            kk = ((unsigned long long)mono << 12) | (unsigned)(4095 - idx);
        }
        key[j] = kk;
    }
    for (int it = 0; it < KSEL; ++it) {
        unsigned long long bk = 0ULL;
        #pragma unroll
        for (int j = 0; j < 35; ++j) bk = key[j] > bk ? key[j] : bk;
        #pragma unroll
        for (int m = 1; m < 64; m <<= 1) {
            unsigned long long o = __shfl_xor(bk, m, 64);
            bk = o > bk ? o : bk;
        }
        #pragma unroll
        for (int j = 0; j < 35; ++j) if (key[j] == bk) key[j] = 0ULL;
        if (l == 0) {
            int idx = 4095 - (int)(bk & 0xFFFULL);
            int h = (idx / 48) * 8; if (h > 320) h = 320;
            int w = (idx % 48) * 8; if (w > 320) w = 320;
            coords[(b*KSEL + it)*2 + 0] = h;
            coords[(b*KSEL + it)*2 + 1] = w;
        }
    }
}

// ---------------------------------------------------------------------------
// Kernel 3: conv1+ReLU + decimated column/row sums -> S[32][3][3] per patch.
// Thread layout: wave w = icg (8 ic), lane = iy*2 + xh (32 rows x 2 halves).
// Each thread: 8 ic x 16 ix. LDS input tile float4-XOR-swizzled so the
// ds_read_b128 column reads spread across banks.
// ---------------------------------------------------------------------------
__global__ __launch_bounds__(256, 2) void k_encode(const float* __restrict__ x,
    const float* __restrict__ w1, const float* __restrict__ b1,
    const int* __restrict__ coords, float* __restrict__ sbuf)
{
    __shared__ float4 sin4[3*66*RPITCH];   // [c][row 0..65][17 f4], swizzled
    __shared__ float  s_S[32*9];

    int p    = blockIdx.x;
    int bimg = p >> 4;
    int tid  = threadIdx.x;
    int h0 = coords[p*2 + 0];
    int w0 = coords[p*2 + 1];

    float4 z4 = make_float4(0.f, 0.f, 0.f, 0.f);
    for (int i = tid; i < 3*66*RPITCH; i += 256) sin4[i] = z4;
    __syncthreads();

    // stage 3x64x64 patch, swizzled scalar LDS writes (data at row y+1, col x+1)
    float* sinf = (float*)sin4;
    #pragma unroll
    for (int it = 0; it < 12; ++it) {
        int fi  = tid + it*256;           // 0..3071
        int c   = fi >> 10;
        int rem = fi & 1023;
        int y   = rem >> 4;
        int x4  = rem & 15;
        float4 v = *reinterpret_cast<const float4*>(
            x + (((size_t)(bimg*3 + c)*384 + (h0 + y))*384 + w0 + x4*4));
        int r  = y + 1;
        int sw = (r >> 1) & 7;
        float vals[4] = {v.x, v.y, v.z, v.w};
        #pragma unroll
        for (int e = 0; e < 4; ++e) {
            int pcol = x4*4 + 1 + e;
            int k  = pcol >> 2, bb = pcol & 3;
            int ks = (k < 16) ? ((k & 8) | ((k & 7) ^ sw)) : 16;
            sinf[((c*66 + r)*RPITCH + ks)*4 + bb] = vals[e];
        }
    }
    __syncthreads();

    int lane = tid & 63;
    int iy   = lane >> 1;     // conv1 output row 0..31
    int xh   = lane & 1;      // which 16-col half
    int icg  = __builtin_amdgcn_readfirstlane(tid >> 6);  // wave's ic group

    float acc[8][16];
    #pragma unroll
    for (int i = 0; i < 8; ++i)
        #pragma unroll
        for (int t = 0; t < 16; ++t) acc[i][t] = 0.f;

    const float* w1g = w1 + icg*8*27;

    for (int ch = 0; ch < 3; ++ch) {
        for (int ky = 0; ky < 3; ++ky) {
            int r    = 2*iy + ky;                // padded input row
            int sw   = (r >> 1) & 7;
            int base = (ch*66 + r)*RPITCH;
            float s[33];                          // padded cols 32xh .. 32xh+32
            #pragma unroll
            for (int j = 0; j < 8; ++j) {
                float4 v = sin4[base + (8*xh | (j ^ sw))];
                s[4*j+0] = v.x; s[4*j+1] = v.y; s[4*j+2] = v.z; s[4*j+3] = v.w;
            }
            {
                int k  = 8*xh + 8;
                int ks = (k < 16) ? ((k & 8) | ((k & 7) ^ sw)) : 16;
                s[32] = sinf[(base + ks)*4];
            }
            const float* wp = w1g + ch*9 + ky*3;  // wave-uniform -> s_loads
            #pragma unroll
            for (int i = 0; i < 8; ++i) {
                float wA = wp[i*27 + 0];
                float wB = wp[i*27 + 1];
                float wC = wp[i*27 + 2];
                #pragma unroll
                for (int t = 0; t < 16; ++t)
                    acc[i][t] = fmaf(s[2*t], wA,
                                 fmaf(s[2*t+1], wB,
                                  fmaf(s[2*t+2], wC, acc[i][t])));
            }
        }
    }

    // bias + ReLU + column-parity sums. global ix = 16*xh + t; parity = t&1.
    // c(kx=1): even ix; c(kx=2): odd ix; c(kx=0): odd ix except ix==31.
    float R[8][3];
    #pragma unroll
    for (int i = 0; i < 8; ++i) {
        float bias = b1[icg*8 + i];
        float c1 = 0.f, c2 = 0.f, vlast = 0.f;
        #pragma unroll
        for (int t = 0; t < 16; ++t) {
            float v = fmaxf(acc[i][t] + bias, 0.f);
            if (t & 1) c2 += v; else c1 += v;
            if (t == 15) vlast = v;
        }
        R[i][0] = c2 - (xh ? vlast : 0.f);
        R[i][1] = c1;
        R[i][2] = c2;
    }

    // reduce over xh (m=1), grab iy=31 row, then reduce over iy keeping parity
    #pragma unroll
    for (int i = 0; i < 8; ++i)
        #pragma unroll
        for (int k = 0; k < 3; ++k)
            R[i][k] += __shfl_xor(R[i][k], 1, 64);

    float c31[8][3];
    #pragma unroll
    for (int i = 0; i < 8; ++i)
        #pragma unroll
        for (int k = 0; k < 3; ++k)
            c31[i][k] = __shfl(R[i][k], 62, 64);   // lane 62 = (iy=31, xh=0)

    #pragma unroll
    for (int m = 4; m < 64; m <<= 1)
        #pragma unroll
        for (int i = 0; i < 8; ++i)
            #pragma unroll
            for (int k = 0; k < 3; ++k)
                R[i][k] += __shfl_xor(R[i][k], m, 64);

    // rows: ky=1 <- even-iy class; ky=2 <- odd class; ky=0 <- odd minus iy=31
    if (lane == 0) {                 // iy=0: even class
        #pragma unroll
        for (int i = 0; i < 8; ++i)
            #pragma unroll
            for (int k = 0; k < 3; ++k)
                s_S[(icg*8 + i)*9 + 3 + k] = R[i][k];
    } else if (lane == 2) {          // iy=1: odd class
        #pragma unroll
        for (int i = 0; i < 8; ++i)
            #pragma unroll
            for (int k = 0; k < 3; ++k) {
                s_S[(icg*8 + i)*9 + 0 + k] = R[i][k] - c31[i][k];
                s_S[(icg*8 + i)*9 + 6 + k] = R[i][k];
            }
    }
    __syncthreads();

    for (int i = tid; i < 288; i += 256)
        sbuf[(size_t)p*288 + i] = s_S[i];
}

// ---------------------------------------------------------------------------
// Kernel 4: per batch: Ssum = sum_k S_k, then out = b2 + w2*Ssum / 4096
// (matvec commutes with the patch mean).
// ---------------------------------------------------------------------------
__global__ __launch_bounds__(256) void k_reduce(const float* __restrict__ sbuf,
    const float* __restrict__ w2, const float* __restrict__ b2,
    float* __restrict__ out)
{
    __shared__ float Ssum[288];
    __shared__ float s_part[256];
    int b = blockIdx.x, tid = threadIdx.x;

    for (int i = tid; i < 288; i += 256) {
        float s = 0.f;
        #pragma unroll
        for (int k = 0; k < KSEL; ++k)
            s += sbuf[(size_t)(b*KSEL + k)*288 + i];
        Ssum[i] = s;
    }
    __syncthreads();

    int oc = tid & 63, q = tid >> 6;
    const float4* w4 = reinterpret_cast<const float4*>(w2 + oc*288 + q*72);
    const float4* S4 = reinterpret_cast<const float4*>(Ssum + q*72);
    float a = 0.f;
    #pragma unroll
    for (int t = 0; t < 18; ++t) {
        float4 wv = w4[t];
        float4 sv = S4[t];
        a = fmaf(wv.x, sv.x, fmaf(wv.y, sv.y,
             fmaf(wv.z, sv.z, fmaf(wv.w, sv.w, a))));
    }
    s_part[tid] = a;
    __syncthreads();
    if (tid < 64) {
        float t = s_part[tid] + s_part[64 + tid] + s_part[128 + tid] + s_part[192 + tid];
        out[b*64 + tid] = b2[tid] + t * (1.0f/4096.0f);
    }
}

extern "C" void kernel_launch(void* const* d_in, const int* in_sizes, int n_in,
                              void* d_out, int out_size, void* d_ws, size_t ws_size,
                              hipStream_t stream)
{
    const float* x  = (const float*)d_in[0];
    const float* w1 = (const float*)d_in[1];
    const float* b1 = (const float*)d_in[2];
    const float* w2 = (const float*)d_in[3];
    const float* b2 = (const float*)d_in[4];
    float* out = (float*)d_out;

    char* ws = (char*)d_ws;
    int*   coords = (int*)ws;                    // 4096 B
    float* var    = (float*)(ws + 4096);         // 282,752 B (dead after k_topk)
    float* sbuf   = (float*)(ws + 4096);         // 589,824 B (overlaps var)

    k_var   <<<dim3(24, NB), 256, 0, stream>>>(x, var);
    k_topk  <<<NB,            64, 0, stream>>>(var, coords);
    k_encode<<<NB*KSEL,      256, 0, stream>>>(x, w1, b1, coords, sbuf);
    k_reduce<<<NB,           256, 0, stream>>>(sbuf, w2, b2, out);
}

// Round 3
// 66.270 us; speedup vs baseline: 1.5814x; 1.1137x over previous
//
#include <hip/hip_runtime.h>
#include <math.h>

#define NB 32
#define GH 47
#define GW 47
#define NWIN (GH*GW)   // 2209
#define KSEL 16
#define RPITCH 17      // float4 per LDS row in k_encode (68 floats)
#define SEG 48         // 8-wide horizontal segments per row

// ---------------------------------------------------------------------------
// Kernel 1: per-window variance via separable f64 sums.
// Non-overlapping 8-wide segment sums (each input float read once
// horizontally); window(gx) = seg[gx] + seg[gx+1].
// block = (gyp, b): windows gy in {2gyp, 2gyp+1}, all 47 gx.
// ---------------------------------------------------------------------------
__global__ __launch_bounds__(256) void k_var(const float* __restrict__ x,
                                             float* __restrict__ var)
{
    __shared__ double hs [3][24][SEG];
    __shared__ double hs2[3][24][SEG];
    int gyp = blockIdx.x;     // 0..23
    int b   = blockIdx.y;
    int tid = threadIdx.x;
    int R0  = gyp * 16;

    // segment sums: task = (c, rr, sg)
    for (int tau = tid; tau < 3*24*SEG; tau += 256) {
        int sg = tau % SEG;
        int t2 = tau / SEG;
        int rr = t2 % 24;
        int c  = t2 / 24;
        int row = R0 + rr;
        double s = 0.0, s2 = 0.0;
        if (row < 384) {
            const float* px = x + (((size_t)(b*3 + c)*384 + row)*384 + sg*8);
            #pragma unroll
            for (int q = 0; q < 2; ++q) {
                float4 v = *reinterpret_cast<const float4*>(px + q*4);
                double a0 = v.x, a1 = v.y, a2 = v.z, a3 = v.w;
                s  += a0 + a1 + a2 + a3;
                s2 = fma(a0,a0, fma(a1,a1, fma(a2,a2, fma(a3,a3, s2))));
            }
        }
        hs [c][rr][sg] = s;
        hs2[c][rr][sg] = s2;
    }
    __syncthreads();

    if (tid < 188) {
        int which = tid & 1;           // 0 -> sum, 1 -> sum of squares
        int rest  = tid >> 1;          // 0..93
        int gx = rest % 47, g = rest / 47;
        int gy = gyp*2 + g;
        if (gy < GH) {
            const double* base = which ? &hs2[0][0][0] : &hs[0][0][0];
            double S = 0.0;
            #pragma unroll
            for (int c = 0; c < 3; ++c)
                #pragma unroll
                for (int r = 0; r < 16; ++r) {
                    const double* rp = base + ((c*24) + (g*8 + r))*SEG + gx;
                    S += rp[0] + rp[1];
                }
            double P = __shfl_xor(S, 1, 64);   // partner's value
            if (which == 0) {
                // S = sum, P = sum of squares
                var[(size_t)b*NWIN + gy*GW + gx] =
                    (float)((P - S*S/768.0) / 767.0);
            }
        }
    }
}

// ---------------------------------------------------------------------------
// Kernel 2: fused {per-block top-(k+1) selection} + conv1+ReLU + decimated
// sums -> S[32][3][3] per patch.
// Phase 0: wave 0 runs the u64-key iterative argmax for k+1 rounds (block
// p needs only its own k-th coordinate) while waves 1-3 zero-fill LDS.
// Phase 1: stage 3x64x64 patch (XOR-swizzled float4 layout).
// Phase 2: wave w = icg (8 ic), lane = iy*2 + xh; each thread 8 ic x 16 ix.
// ---------------------------------------------------------------------------
__global__ __launch_bounds__(256, 2) void k_encode(const float* __restrict__ x,
    const float* __restrict__ w1, const float* __restrict__ b1,
    const float* __restrict__ var, float* __restrict__ sbuf)
{
    __shared__ float4 sin4[3*66*RPITCH];   // [c][row 0..65][17 f4], swizzled
    __shared__ float  s_S[32*9];
    __shared__ int    s_hw[2];

    int p    = blockIdx.x;
    int bimg = p >> 4;
    int krank = p & 15;
    int tid  = threadIdx.x;

    if (tid < 64) {
        // ---- top-(krank+1) selection, register-resident u64 keys ----
        // key = (monotonic-f32-bits << 12) | (4095 - idx): max => largest v,
        // tie -> smaller idx (stable like jax.lax.top_k).
        int l = tid;
        const float* vb = var + (size_t)bimg*NWIN;
        unsigned long long key[35];
        #pragma unroll
        for (int j = 0; j < 35; ++j) {
            int idx = j*64 + l;
            unsigned long long kk = 0ULL;
            if (idx < NWIN) {
                unsigned u = __float_as_uint(vb[idx]);
                unsigned mono = u ^ ((unsigned)((int)u >> 31) | 0x80000000u);
                kk = ((unsigned long long)mono << 12) | (unsigned)(4095 - idx);
            }
            key[j] = kk;
        }
        unsigned long long bk = 0ULL;
        for (int it = 0; ; ++it) {
            bk = 0ULL;
            #pragma unroll
            for (int j = 0; j < 35; ++j) bk = key[j] > bk ? key[j] : bk;
            #pragma unroll
            for (int m = 1; m < 64; m <<= 1) {
                unsigned long long o = __shfl_xor(bk, m, 64);
                bk = o > bk ? o : bk;
            }
            if (it == krank) break;
            #pragma unroll
            for (int j = 0; j < 35; ++j) if (key[j] == bk) key[j] = 0ULL;
        }
        if (l == 0) {
            int idx = 4095 - (int)(bk & 0xFFFULL);
            int h = (idx / 48) * 8; if (h > 320) h = 320;  // buggy /48 + clamp
            int w = (idx % 48) * 8; if (w > 320) w = 320;
            s_hw[0] = h; s_hw[1] = w;
        }
    } else {
        float4 z4 = make_float4(0.f, 0.f, 0.f, 0.f);
        for (int i = tid - 64; i < 3*66*RPITCH; i += 192) sin4[i] = z4;
    }
    __syncthreads();

    int h0 = s_hw[0];
    int w0 = s_hw[1];

    // stage 3x64x64 patch, swizzled scalar LDS writes (data at row y+1, col x+1)
    float* sinf = (float*)sin4;
    #pragma unroll
    for (int it = 0; it < 12; ++it) {
        int fi  = tid + it*256;           // 0..3071
        int c   = fi >> 10;
        int rem = fi & 1023;
        int y   = rem >> 4;
        int x4  = rem & 15;
        float4 v = *reinterpret_cast<const float4*>(
            x + (((size_t)(bimg*3 + c)*384 + (h0 + y))*384 + w0 + x4*4));
        int r  = y + 1;
        int sw = (r >> 1) & 7;
        float vals[4] = {v.x, v.y, v.z, v.w};
        #pragma unroll
        for (int e = 0; e < 4; ++e) {
            int pcol = x4*4 + 1 + e;
            int k  = pcol >> 2, bb = pcol & 3;
            int ks = (k < 16) ? ((k & 8) | ((k & 7) ^ sw)) : 16;
            sinf[((c*66 + r)*RPITCH + ks)*4 + bb] = vals[e];
        }
    }
    __syncthreads();

    int lane = tid & 63;
    int iy   = lane >> 1;     // conv1 output row 0..31
    int xh   = lane & 1;      // which 16-col half
    int icg  = __builtin_amdgcn_readfirstlane(tid >> 6);  // wave's ic group

    float acc[8][16];
    #pragma unroll
    for (int i = 0; i < 8; ++i)
        #pragma unroll
        for (int t = 0; t < 16; ++t) acc[i][t] = 0.f;

    const float* w1g = w1 + icg*8*27;

    for (int ch = 0; ch < 3; ++ch) {
        for (int ky = 0; ky < 3; ++ky) {
            int r    = 2*iy + ky;                // padded input row
            int sw   = (r >> 1) & 7;
            int base = (ch*66 + r)*RPITCH;
            float s[33];                          // padded cols 32xh .. 32xh+32
            #pragma unroll
            for (int j = 0; j < 8; ++j) {
                float4 v = sin4[base + (8*xh | (j ^ sw))];
                s[4*j+0] = v.x; s[4*j+1] = v.y; s[4*j+2] = v.z; s[4*j+3] = v.w;
            }
            {
                int k  = 8*xh + 8;
                int ks = (k < 16) ? ((k & 8) | ((k & 7) ^ sw)) : 16;
                s[32] = sinf[(base + ks)*4];
            }
            const float* wp = w1g + ch*9 + ky*3;  // wave-uniform -> s_loads
            #pragma unroll
            for (int i = 0; i < 8; ++i) {
                float wA = wp[i*27 + 0];
                float wB = wp[i*27 + 1];
                float wC = wp[i*27 + 2];
                #pragma unroll
                for (int t = 0; t < 16; ++t)
                    acc[i][t] = fmaf(s[2*t], wA,
                                 fmaf(s[2*t+1], wB,
                                  fmaf(s[2*t+2], wC, acc[i][t])));
            }
        }
    }

    // bias + ReLU + column-parity sums. global ix = 16*xh + t; parity = t&1.
    float R[8][3];
    #pragma unroll
    for (int i = 0; i < 8; ++i) {
        float bias = b1[icg*8 + i];
        float c1 = 0.f, c2 = 0.f, vlast = 0.f;
        #pragma unroll
        for (int t = 0; t < 16; ++t) {
            float v = fmaxf(acc[i][t] + bias, 0.f);
            if (t & 1) c2 += v; else c1 += v;
            if (t == 15) vlast = v;
        }
        R[i][0] = c2 - (xh ? vlast : 0.f);
        R[i][1] = c1;
        R[i][2] = c2;
    }

    // reduce over xh (m=1), grab iy=31 row, then reduce over iy keeping parity
    #pragma unroll
    for (int i = 0; i < 8; ++i)
        #pragma unroll
        for (int k = 0; k < 3; ++k)
            R[i][k] += __shfl_xor(R[i][k], 1, 64);

    float c31[8][3];
    #pragma unroll
    for (int i = 0; i < 8; ++i)
        #pragma unroll
        for (int k = 0; k < 3; ++k)
            c31[i][k] = __shfl(R[i][k], 62, 64);   // lane 62 = (iy=31, xh=0)

    #pragma unroll
    for (int m = 4; m < 64; m <<= 1)
        #pragma unroll
        for (int i = 0; i < 8; ++i)
            #pragma unroll
            for (int k = 0; k < 3; ++k)
                R[i][k] += __shfl_xor(R[i][k], m, 64);

    // rows: ky=1 <- even-iy class; ky=2 <- odd class; ky=0 <- odd minus iy=31
    if (lane == 0) {                 // iy=0: even class
        #pragma unroll
        for (int i = 0; i < 8; ++i)
            #pragma unroll
            for (int k = 0; k < 3; ++k)
                s_S[(icg*8 + i)*9 + 3 + k] = R[i][k];
    } else if (lane == 2) {          // iy=1: odd class
        #pragma unroll
        for (int i = 0; i < 8; ++i)
            #pragma unroll
            for (int k = 0; k < 3; ++k) {
                s_S[(icg*8 + i)*9 + 0 + k] = R[i][k] - c31[i][k];
                s_S[(icg*8 + i)*9 + 6 + k] = R[i][k];
            }
    }
    __syncthreads();

    for (int i = tid; i < 288; i += 256)
        sbuf[(size_t)p*288 + i] = s_S[i];
}

// ---------------------------------------------------------------------------
// Kernel 3: per batch: Ssum = sum_k S_k, then out = b2 + w2*Ssum / 4096
// (matvec commutes with the patch mean).
// ---------------------------------------------------------------------------
__global__ __launch_bounds__(256) void k_reduce(const float* __restrict__ sbuf,
    const float* __restrict__ w2, const float* __restrict__ b2,
    float* __restrict__ out)
{
    __shared__ float Ssum[288];
    __shared__ float s_part[256];
    int b = blockIdx.x, tid = threadIdx.x;

    for (int i = tid; i < 288; i += 256) {
        float s = 0.f;
        #pragma unroll
        for (int k = 0; k < KSEL; ++k)
            s += sbuf[(size_t)(b*KSEL + k)*288 + i];
        Ssum[i] = s;
    }
    __syncthreads();

    int oc = tid & 63, q = tid >> 6;
    const float4* w4 = reinterpret_cast<const float4*>(w2 + oc*288 + q*72);
    const float4* S4 = reinterpret_cast<const float4*>(Ssum + q*72);
    float a = 0.f;
    #pragma unroll
    for (int t = 0; t < 18; ++t) {
        float4 wv = w4[t];
        float4 sv = S4[t];
        a = fmaf(wv.x, sv.x, fmaf(wv.y, sv.y,
             fmaf(wv.z, sv.z, fmaf(wv.w, sv.w, a))));
    }
    s_part[tid] = a;
    __syncthreads();
    if (tid < 64) {
        float t = s_part[tid] + s_part[64 + tid] + s_part[128 + tid] + s_part[192 + tid];
        out[b*64 + tid] = b2[tid] + t * (1.0f/4096.0f);
    }
}

extern "C" void kernel_launch(void* const* d_in, const int* in_sizes, int n_in,
                              void* d_out, int out_size, void* d_ws, size_t ws_size,
                              hipStream_t stream)
{
    const float* x  = (const float*)d_in[0];
    const float* w1 = (const float*)d_in[1];
    const float* b1 = (const float*)d_in[2];
    const float* w2 = (const float*)d_in[3];
    const float* b2 = (const float*)d_in[4];
    float* out = (float*)d_out;

    char* ws = (char*)d_ws;
    float* var  = (float*)ws;                      // 32*2209*4 = 282,752 B
    float* sbuf = (float*)(ws + 283904);           // 512*288*4 = 589,824 B

    k_var   <<<dim3(24, NB), 256, 0, stream>>>(x, var);
    k_encode<<<NB*KSEL,      256, 0, stream>>>(x, w1, b1, var, sbuf);
    k_reduce<<<NB,           256, 0, stream>>>(sbuf, w2, b2, out);
}

// Round 4
// 63.893 us; speedup vs baseline: 1.6403x; 1.0372x over previous
//
#include <hip/hip_runtime.h>
#include <math.h>

#define NB 32
#define GH 47
#define GW 47
#define NWIN (GH*GW)   // 2209
#define KSEL 16
#define RPITCH 17      // float4 per LDS row in k_encode (68 floats)
#define SEG 48         // 8-wide horizontal segments per row

// ---------------------------------------------------------------------------
// Kernel 1: per-window variance via separable f64 sums (unchanged, verified).
// ---------------------------------------------------------------------------
__global__ __launch_bounds__(256) void k_var(const float* __restrict__ x,
                                             float* __restrict__ var)
{
    __shared__ double hs [3][24][SEG];
    __shared__ double hs2[3][24][SEG];
    int gyp = blockIdx.x;     // 0..23
    int b   = blockIdx.y;
    int tid = threadIdx.x;
    int R0  = gyp * 16;

    for (int tau = tid; tau < 3*24*SEG; tau += 256) {
        int sg = tau % SEG;
        int t2 = tau / SEG;
        int rr = t2 % 24;
        int c  = t2 / 24;
        int row = R0 + rr;
        double s = 0.0, s2 = 0.0;
        if (row < 384) {
            const float* px = x + (((size_t)(b*3 + c)*384 + row)*384 + sg*8);
            #pragma unroll
            for (int q = 0; q < 2; ++q) {
                float4 v = *reinterpret_cast<const float4*>(px + q*4);
                double a0 = v.x, a1 = v.y, a2 = v.z, a3 = v.w;
                s  += a0 + a1 + a2 + a3;
                s2 = fma(a0,a0, fma(a1,a1, fma(a2,a2, fma(a3,a3, s2))));
            }
        }
        hs [c][rr][sg] = s;
        hs2[c][rr][sg] = s2;
    }
    __syncthreads();

    if (tid < 188) {
        int which = tid & 1;
        int rest  = tid >> 1;
        int gx = rest % 47, g = rest / 47;
        int gy = gyp*2 + g;
        if (gy < GH) {
            const double* base = which ? &hs2[0][0][0] : &hs[0][0][0];
            double S = 0.0;
            #pragma unroll
            for (int c = 0; c < 3; ++c)
                #pragma unroll
                for (int r = 0; r < 16; ++r) {
                    const double* rp = base + ((c*24) + (g*8 + r))*SEG + gx;
                    S += rp[0] + rp[1];
                }
            double P = __shfl_xor(S, 1, 64);
            if (which == 0) {
                var[(size_t)b*NWIN + gy*GW + gx] =
                    (float)((P - S*S/768.0) / 767.0);
            }
        }
    }
}

// ---------------------------------------------------------------------------
// Kernel 2: fused {top-(k+1) selection} + conv1+ReLU + decimated sums.
// 512 threads / 8 waves. Wave pair (2g,2g+1) owns ic-group g; thread =
// (iy 0..31, xq 0..3) computes acc[8 ic][8 ix] -> 64 VGPR accumulator,
// no spills (round-3 version spilled ~10 MB of scratch with acc[8][16]).
// ---------------------------------------------------------------------------
__global__ __launch_bounds__(512, 4) void k_encode(const float* __restrict__ x,
    const float* __restrict__ w1, const float* __restrict__ b1,
    const float* __restrict__ var, float* __restrict__ sbuf)
{
    __shared__ float4 sin4[3*66*RPITCH];    // [c][row 0..65][17 f4], swizzled
    __shared__ float  s_part[8][2][8][3];   // [wave][iy-parity][i][kx]
    __shared__ float  s_c31[4][8][3];       // row-31 triple per ic-group
    __shared__ int    s_hw[2];

    int p     = blockIdx.x;
    int bimg  = p >> 4;
    int krank = p & 15;
    int tid   = threadIdx.x;

    if (tid < 64) {
        // ---- top-(krank+1), register-resident u64 keys (bit-identical) ----
        int l = tid;
        const float* vb = var + (size_t)bimg*NWIN;
        unsigned long long key[35];
        #pragma unroll
        for (int j = 0; j < 35; ++j) {
            int idx = j*64 + l;
            unsigned long long kk = 0ULL;
            if (idx < NWIN) {
                unsigned u = __float_as_uint(vb[idx]);
                unsigned mono = u ^ ((unsigned)((int)u >> 31) | 0x80000000u);
                kk = ((unsigned long long)mono << 12) | (unsigned)(4095 - idx);
            }
            key[j] = kk;
        }
        unsigned long long bk = 0ULL;
        for (int it = 0; ; ++it) {
            bk = 0ULL;
            #pragma unroll
            for (int j = 0; j < 35; ++j) bk = key[j] > bk ? key[j] : bk;
            #pragma unroll
            for (int m = 1; m < 64; m <<= 1) {
                unsigned long long o = __shfl_xor(bk, m, 64);
                bk = o > bk ? o : bk;
            }
            if (it == krank) break;
            #pragma unroll
            for (int j = 0; j < 35; ++j) if (key[j] == bk) key[j] = 0ULL;
        }
        if (l == 0) {
            int idx = 4095 - (int)(bk & 0xFFFULL);
            int h = (idx / 48) * 8; if (h > 320) h = 320;  // buggy /48 + clamp
            int w = (idx % 48) * 8; if (w > 320) w = 320;
            s_hw[0] = h; s_hw[1] = w;
        }
    } else {
        float4 z4 = make_float4(0.f, 0.f, 0.f, 0.f);
        for (int i = tid - 64; i < 3*66*RPITCH; i += 448) sin4[i] = z4;
    }
    __syncthreads();

    int h0 = s_hw[0];
    int w0 = s_hw[1];

    // stage 3x64x64 patch, swizzled scalar LDS writes (data at row y+1, col x+1)
    float* sinf = (float*)sin4;
    #pragma unroll
    for (int it = 0; it < 6; ++it) {
        int fi  = tid + it*512;           // 0..3071
        int c   = fi >> 10;
        int rem = fi & 1023;
        int y   = rem >> 4;
        int x4  = rem & 15;
        float4 v = *reinterpret_cast<const float4*>(
            x + (((size_t)(bimg*3 + c)*384 + (h0 + y))*384 + w0 + x4*4));
        int r  = y + 1;
        int sw = (r >> 1) & 7;
        float vals[4] = {v.x, v.y, v.z, v.w};
        #pragma unroll
        for (int e = 0; e < 4; ++e) {
            int pcol = x4*4 + 1 + e;
            int k  = pcol >> 2, bb = pcol & 3;
            int ks = (k < 16) ? ((k & 8) | ((k & 7) ^ sw)) : 16;
            sinf[((c*66 + r)*RPITCH + ks)*4 + bb] = vals[e];
        }
    }
    __syncthreads();

    int wave = tid >> 6;
    int lane = tid & 63;
    int sub  = wave & 1;
    int icg  = __builtin_amdgcn_readfirstlane(tid >> 7);  // ic-group 0..3
    int iy   = sub*16 + (lane >> 2);   // conv1 output row 0..31
    int xq   = lane & 3;               // 8-col quarter

    float acc[8][8];
    #pragma unroll
    for (int i = 0; i < 8; ++i)
        #pragma unroll
        for (int u = 0; u < 8; ++u) acc[i][u] = 0.f;

    const float* w1g = w1 + icg*8*27;

    for (int ch = 0; ch < 3; ++ch) {
        for (int ky = 0; ky < 3; ++ky) {
            int r    = 2*iy + ky;                // padded input row
            int sw   = (r >> 1) & 7;
            int base = (ch*66 + r)*RPITCH;
            float s[17];                          // padded cols 16xq .. 16xq+16
            #pragma unroll
            for (int j = 0; j < 4; ++j) {
                int k = 4*xq + j;
                float4 v = sin4[base + ((k & 8) | ((k & 7) ^ sw))];
                s[4*j+0] = v.x; s[4*j+1] = v.y; s[4*j+2] = v.z; s[4*j+3] = v.w;
            }
            {
                int k  = 4*xq + 4;
                int ks = (k < 16) ? ((k & 8) | ((k & 7) ^ sw)) : 16;
                s[16] = sinf[(base + ks)*4];
            }
            const float* wp = w1g + ch*9 + ky*3;  // wave-uniform -> s_loads
            #pragma unroll
            for (int i = 0; i < 8; ++i) {
                float wA = wp[i*27 + 0];
                float wB = wp[i*27 + 1];
                float wC = wp[i*27 + 2];
                #pragma unroll
                for (int u = 0; u < 8; ++u)
                    acc[i][u] = fmaf(s[2*u], wA,
                                 fmaf(s[2*u+1], wB,
                                  fmaf(s[2*u+2], wC, acc[i][u])));
            }
        }
    }

    // bias + ReLU + column-parity sums. global ix = 8*xq + u; parity = u&1.
    float R[8][3];
    #pragma unroll
    for (int i = 0; i < 8; ++i) {
        float bias = b1[icg*8 + i];
        float c1 = 0.f, c2 = 0.f, v7 = 0.f;
        #pragma unroll
        for (int u = 0; u < 8; ++u) {
            float v = fmaxf(acc[i][u] + bias, 0.f);
            if (u & 1) c2 += v; else c1 += v;
            if (u == 7) v7 = v;
        }
        R[i][0] = c2 - ((xq == 3) ? v7 : 0.f);   // odd cols minus ix=31
        R[i][1] = c1;                            // even cols
        R[i][2] = c2;                            // odd cols
    }

    // reduce over xq (lane bits 0,1)
    #pragma unroll
    for (int m = 1; m <= 2; m <<= 1)
        #pragma unroll
        for (int i = 0; i < 8; ++i)
            #pragma unroll
            for (int k = 0; k < 3; ++k)
                R[i][k] += __shfl_xor(R[i][k], m, 64);

    // row-31 triple (meaningful in odd waves: lanes 60..63 = iy 31)
    float c31[8][3];
    #pragma unroll
    for (int i = 0; i < 8; ++i)
        #pragma unroll
        for (int k = 0; k < 3; ++k)
            c31[i][k] = __shfl(R[i][k], 60, 64);

    // reduce over iy bits 1..3 (lane bits 3,4,5), preserving iy parity (bit 2)
    #pragma unroll
    for (int m = 8; m < 64; m <<= 1)
        #pragma unroll
        for (int i = 0; i < 8; ++i)
            #pragma unroll
            for (int k = 0; k < 3; ++k)
                R[i][k] += __shfl_xor(R[i][k], m, 64);

    if (lane == 0) {                 // even-iy class of this wave's half
        #pragma unroll
        for (int i = 0; i < 8; ++i)
            #pragma unroll
            for (int k = 0; k < 3; ++k)
                s_part[wave][0][i][k] = R[i][k];
    } else if (lane == 4) {          // odd-iy class
        #pragma unroll
        for (int i = 0; i < 8; ++i)
            #pragma unroll
            for (int k = 0; k < 3; ++k)
                s_part[wave][1][i][k] = R[i][k];
    }
    if (sub == 1 && lane == 8) {
        #pragma unroll
        for (int i = 0; i < 8; ++i)
            #pragma unroll
            for (int k = 0; k < 3; ++k)
                s_c31[icg][i][k] = c31[i][k];
    }
    __syncthreads();

    // S[ic][ky][kx]: ky=1 <- even rows; ky=2 <- odd rows; ky=0 <- odd - row31
    if (tid < 288) {
        int ic = tid / 9, j = tid - ic*9;
        int ky = j / 3, kx = j - ky*3;
        int g = ic >> 3, i = ic & 7;
        float even = s_part[2*g][0][i][kx] + s_part[2*g+1][0][i][kx];
        float odd  = s_part[2*g][1][i][kx] + s_part[2*g+1][1][i][kx];
        float val = (ky == 1) ? even : odd;
        if (ky == 0) val = odd - s_c31[g][i][kx];
        sbuf[(size_t)p*288 + tid] = val;
    }
}

// ---------------------------------------------------------------------------
// Kernel 3: per batch: Ssum = sum_k S_k, then out = b2 + w2*Ssum / 4096
// ---------------------------------------------------------------------------
__global__ __launch_bounds__(256) void k_reduce(const float* __restrict__ sbuf,
    const float* __restrict__ w2, const float* __restrict__ b2,
    float* __restrict__ out)
{
    __shared__ float Ssum[288];
    __shared__ float s_part[256];
    int b = blockIdx.x, tid = threadIdx.x;

    for (int i = tid; i < 288; i += 256) {
        float s = 0.f;
        #pragma unroll
        for (int k = 0; k < KSEL; ++k)
            s += sbuf[(size_t)(b*KSEL + k)*288 + i];
        Ssum[i] = s;
    }
    __syncthreads();

    int oc = tid & 63, q = tid >> 6;
    const float4* w4 = reinterpret_cast<const float4*>(w2 + oc*288 + q*72);
    const float4* S4 = reinterpret_cast<const float4*>(Ssum + q*72);
    float a = 0.f;
    #pragma unroll
    for (int t = 0; t < 18; ++t) {
        float4 wv = w4[t];
        float4 sv = S4[t];
        a = fmaf(wv.x, sv.x, fmaf(wv.y, sv.y,
             fmaf(wv.z, sv.z, fmaf(wv.w, sv.w, a))));
    }
    s_part[tid] = a;
    __syncthreads();
    if (tid < 64) {
        float t = s_part[tid] + s_part[64 + tid] + s_part[128 + tid] + s_part[192 + tid];
        out[b*64 + tid] = b2[tid] + t * (1.0f/4096.0f);
    }
}

extern "C" void kernel_launch(void* const* d_in, const int* in_sizes, int n_in,
                              void* d_out, int out_size, void* d_ws, size_t ws_size,
                              hipStream_t stream)
{
    const float* x  = (const float*)d_in[0];
    const float* w1 = (const float*)d_in[1];
    const float* b1 = (const float*)d_in[2];
    const float* w2 = (const float*)d_in[3];
    const float* b2 = (const float*)d_in[4];
    float* out = (float*)d_out;

    char* ws = (char*)d_ws;
    float* var  = (float*)ws;                      // 32*2209*4 = 282,752 B
    float* sbuf = (float*)(ws + 283904);           // 512*288*4 = 589,824 B

    k_var   <<<dim3(24, NB), 256, 0, stream>>>(x, var);
    k_encode<<<NB*KSEL,      512, 0, stream>>>(x, w1, b1, var, sbuf);
    k_reduce<<<NB,           256, 0, stream>>>(sbuf, w2, b2, out);
}